// Round 1
// baseline (197.861 us; speedup 1.0000x reference)
//
#include <hip/hip_runtime.h>

// Reprojection residual:
//   p7 = poses[cidx[i]]  (t=p7[0:3], qv=p7[3:6], qw=p7[6])
//   pt = points_param[pidx[i]]
//   uv = cross(qv, pt) + qw*pt
//   pc = pt + 2*cross(qv, uv) + t
//   proj = K @ pc ;  pix = proj.xy / proj.z ;  out = pix - observes[i]
//
// 4 points per thread: int4/float4 vectorized streaming loads & stores.
// Pose table is 2000*7*4 = 56 KB -> L1/L2 resident, gather is cheap.

__global__ __launch_bounds__(256) void residual_kernel(
    const float* __restrict__ poses,
    const float* __restrict__ pts,
    const float* __restrict__ obs,
    const float* __restrict__ Km,
    const int*   __restrict__ cidx,
    const int*   __restrict__ pidx,
    float*       __restrict__ out,
    int n4) // number of 4-point groups
{
    int t = blockIdx.x * blockDim.x + threadIdx.x;
    if (t >= n4) return;

    // Wave-uniform K (9 floats, broadcast from cache)
    float k00 = Km[0], k01 = Km[1], k02 = Km[2];
    float k10 = Km[3], k11 = Km[4], k12 = Km[5];
    float k20 = Km[6], k21 = Km[7], k22 = Km[8];

    int4 ci4 = ((const int4*)cidx)[t];
    int4 pi4 = ((const int4*)pidx)[t];
    float4 ob01 = ((const float4*)obs)[2 * t];
    float4 ob23 = ((const float4*)obs)[2 * t + 1];

    int cis[4]  = {ci4.x, ci4.y, ci4.z, ci4.w};
    int pis[4]  = {pi4.x, pi4.y, pi4.z, pi4.w};
    float ob[8] = {ob01.x, ob01.y, ob01.z, ob01.w, ob23.x, ob23.y, ob23.z, ob23.w};

    float res[8];

    #pragma unroll
    for (int j = 0; j < 4; ++j) {
        const float* pp = pts + 3L * (long)pis[j];
        float px = pp[0], py = pp[1], pz = pp[2];

        const float* po = poses + 7L * (long)cis[j];
        float tx = po[0], ty = po[1], tz = po[2];
        float qx = po[3], qy = po[4], qz = po[5], qw = po[6];

        // uv = cross(qv, p) + qw * p
        float ux = qy * pz - qz * py + qw * px;
        float uy = qz * px - qx * pz + qw * py;
        float uz = qx * py - qy * px + qw * pz;

        // pc = p + 2*cross(qv, uv) + t
        float cx = px + 2.0f * (qy * uz - qz * uy) + tx;
        float cy = py + 2.0f * (qz * ux - qx * uz) + ty;
        float cz = pz + 2.0f * (qx * uy - qy * ux) + tz;

        // proj = K @ pc ; pix = proj.xy / proj.z
        float w    = k20 * cx + k21 * cy + k22 * cz;
        float invw = 1.0f / w;
        float u    = (k00 * cx + k01 * cy + k02 * cz) * invw;
        float v    = (k10 * cx + k11 * cy + k12 * cz) * invw;

        res[2 * j]     = u - ob[2 * j];
        res[2 * j + 1] = v - ob[2 * j + 1];
    }

    float4* o = (float4*)(out + 8L * (long)t);
    o[0] = make_float4(res[0], res[1], res[2], res[3]);
    o[1] = make_float4(res[4], res[5], res[6], res[7]);
}

extern "C" void kernel_launch(void* const* d_in, const int* in_sizes, int n_in,
                              void* d_out, int out_size, void* d_ws, size_t ws_size,
                              hipStream_t stream) {
    const float* poses = (const float*)d_in[0];
    const float* pts   = (const float*)d_in[1];
    const float* obs   = (const float*)d_in[2];
    const float* Km    = (const float*)d_in[3];
    const int*   cidx  = (const int*)d_in[4];
    const int*   pidx  = (const int*)d_in[5];
    float* out = (float*)d_out;

    int P  = in_sizes[4];      // number of points (cidx element count)
    int n4 = P / 4;            // P = 5,000,000 -> divisible by 4

    const int block = 256;
    int grid = (n4 + block - 1) / block;
    residual_kernel<<<grid, block, 0, stream>>>(poses, pts, obs, Km, cidx, pidx, out, n4);
}